// Round 3
// baseline (411.235 us; speedup 1.0000x reference)
//
#include <hip/hip_runtime.h>
#include <math.h>

typedef __bf16 bf16x8 __attribute__((ext_vector_type(8)));
typedef float f32x4 __attribute__((ext_vector_type(4)));
typedef unsigned short ushort_t;

static __device__ __forceinline__ unsigned short f2bf(float f) {
  union { float f; unsigned int u; } c; c.f = f;
  unsigned int u = c.u;
  unsigned int r = u + 0x7FFFu + ((u >> 16) & 1u);
  return (unsigned short)(r >> 16);
}
static __device__ __forceinline__ float bf2f(unsigned short s) {
  union { unsigned int u; float f; } c; c.u = ((unsigned int)s) << 16; return c.f;
}

// ---------------- constants ----------------
#define CDIM 180      // true channel dim
#define CPAD 192      // padded: 6 heads * 32
#define NHEAD 6
#define NTOK 65536
#define KVPAD 384     // k(192) | v(192)

// ---------------- prep: pad/permute weights (f32 -> bf16) + kv bias row ----------------
__global__ __launch_bounds__(256) void prep_k(
    const float* __restrict__ q_w, const float* __restrict__ q_b,
    const float* __restrict__ kv_w, const float* __restrict__ kv_b,
    const float* __restrict__ p_w, const float* __restrict__ p_b,
    ushort_t* __restrict__ qwp, ushort_t* __restrict__ kvwp, ushort_t* __restrict__ pwp,
    float* __restrict__ qbp, float* __restrict__ kvbp, float* __restrict__ pbp,
    ushort_t* __restrict__ kv_bias_row)
{
  int i = blockIdx.x * 256 + threadIdx.x;
  if (i < 36864) { // qwp[192][192]
    int k = i / 192, cn = i % 192, h = cn >> 5, d = cn & 31;
    qwp[i] = (k < CDIM && d < 30) ? f2bf(q_w[k * CDIM + h * 30 + d]) : (ushort_t)0;
    return;
  }
  i -= 36864;
  if (i < 73728) { // kvwp[192][384]
    int k = i / 384, cn = i % 384;
    int part = (cn >= 192) ? 1 : 0, c2 = cn - part * 192;
    int h = c2 >> 5, d = c2 & 31;
    kvwp[k * 384 + cn] = (k < CDIM && d < 30) ? f2bf(kv_w[k * 360 + part * 180 + h * 30 + d]) : (ushort_t)0;
    return;
  }
  i -= 73728;
  if (i < 36864) { // pwp[192][192], row-permuted
    int r = i / 192, n = i % 192, h = r >> 5, d = r & 31;
    pwp[i] = (d < 30 && n < CDIM) ? f2bf(p_w[(h * 30 + d) * CDIM + n]) : (ushort_t)0;
    return;
  }
  i -= 36864;
  if (i < 192) { int h = i >> 5, d = i & 31; qbp[i] = (d < 30) ? q_b[h * 30 + d] : 0.f; return; }
  i -= 192;
  if (i < 384) {
    int part = (i >= 192) ? 1 : 0, c2 = i - part * 192, h = c2 >> 5, d = c2 & 31;
    kvbp[i] = (d < 30) ? kv_b[part * 180 + h * 30 + d] : 0.f; return;
  }
  i -= 384;
  if (i < 192) { pbp[i] = (i < CDIM) ? p_b[i] : 0.f; return; }
  i -= 192;
  if (i < 384) { // kv bias row (zero-padded patch positions: xn==0 -> kv = bias)
    int part = (i >= 192) ? 1 : 0, c2 = i - part * 192, h = c2 >> 5, d = c2 & 31;
    kv_bias_row[i] = (d < 30) ? f2bf(kv_b[part * 180 + h * 30 + d]) : (ushort_t)0;
    return;
  }
}

// ---------------- LayerNorm: x[65536][180] f32 -> xn_p[65536][192] bf16 ----------------
__global__ __launch_bounds__(256) void ln_k(const float* __restrict__ x,
    const float* __restrict__ nw, const float* __restrict__ nb,
    ushort_t* __restrict__ xn)
{
  const int lane = threadIdx.x & 63, wave = threadIdx.x >> 6;
  const int row = blockIdx.x * 4 + wave;
  const float* xr = x + (size_t)row * CDIM;
  float f0 = xr[lane];
  float f1 = xr[lane + 64];
  float f2 = (lane < 52) ? xr[lane + 128] : 0.f;
  float sum = f0 + f1 + f2;
  float sq = f0 * f0 + f1 * f1 + f2 * f2;
  #pragma unroll
  for (int off = 1; off < 64; off <<= 1) {
    sum += __shfl_xor(sum, off, 64);
    sq  += __shfl_xor(sq, off, 64);
  }
  const float inv_n = 1.0f / 180.0f;
  float mean = sum * inv_n;
  float var = sq * inv_n - mean * mean;
  float rs = rsqrtf(var + 1e-5f);
  ushort_t* xo = xn + (size_t)row * CPAD;
  #pragma unroll
  for (int e = 0; e < 3; ++e) {
    int col = lane + e * 64;
    float v = 0.f;
    if (col < CDIM) v = (( (e==0)?f0 : (e==1)?f1 : f2 ) - mean) * rs * nw[col] + nb[col];
    xo[col] = f2bf(v);
  }
}

// ---------------- generic MFMA GEMM ----------------
// MODE 0: Q    : A=xn_p[65536][192], W=qwp[192][192],  outb=q_tok[65536][192] bf16
// MODE 1: KV   : A=xn_p[65536][192], W=kvwp[192][384], outb=kv_tok[65536][384] bf16
// MODE 2: PROJ : A=ao[65536][192],  W=pwp[192][192],  outf=d_out[65536][180] f32 + resid(x f32)
template<int MODE>
__global__ __launch_bounds__(256) void gemm_k(const ushort_t* __restrict__ A,
    const ushort_t* __restrict__ Wp, const float* __restrict__ bias,
    ushort_t* __restrict__ outb, float* __restrict__ outf,
    const float* __restrict__ resid)
{
  constexpr int NPAD = (MODE == 1) ? 384 : 192;
  __shared__ __align__(16) ushort_t aS[128 * 40];
  __shared__ __align__(16) ushort_t bS[64 * 40];
  const int tid = threadIdx.x;
  const int lane = tid & 63, wave = tid >> 6;
  const int quad = lane >> 4, l16 = lane & 15;
  const int wm = wave & 1, wn = wave >> 1;
  const int bm = blockIdx.x, bn = blockIdx.y;

  f32x4 acc[4][2] = {};

  for (int ks = 0; ks < 6; ++ks) {
    const int kbase = ks * 32;
    // stage A tile (128 rows x 32 cols), 16B vector loads
    #pragma unroll
    for (int tt = 0; tt < 2; ++tt) {
      int tsk = tid + tt * 256;
      int row = tsk >> 2, seg = tsk & 3;
      int arow = bm * 128 + row;
      uint4 val = *reinterpret_cast<const uint4*>(A + (size_t)arow * CPAD + kbase + seg * 8);
      *reinterpret_cast<uint4*>(&aS[row * 40 + seg * 8]) = val;
    }
    // stage B tile (32 k x 64 n), transposed to bS[n][k]
    {
      int k = tid & 31, cg = tid >> 5;
      union { uint4 v; ushort_t s[8]; } u;
      u.v = *reinterpret_cast<const uint4*>(Wp + (size_t)(kbase + k) * NPAD + bn * 64 + cg * 8);
      #pragma unroll
      for (int j = 0; j < 8; ++j) bS[(cg * 8 + j) * 40 + k] = u.s[j];
    }
    __syncthreads();
    bf16x8 af[4], bfr[2];
    #pragma unroll
    for (int mt = 0; mt < 4; ++mt)
      af[mt] = *reinterpret_cast<const bf16x8*>(&aS[(wm * 64 + mt * 16 + l16) * 40 + quad * 8]);
    #pragma unroll
    for (int nt = 0; nt < 2; ++nt)
      bfr[nt] = *reinterpret_cast<const bf16x8*>(&bS[(wn * 32 + nt * 16 + l16) * 40 + quad * 8]);
    #pragma unroll
    for (int mt = 0; mt < 4; ++mt)
      #pragma unroll
      for (int nt = 0; nt < 2; ++nt)
        acc[mt][nt] = __builtin_amdgcn_mfma_f32_16x16x32_bf16(af[mt], bfr[nt], acc[mt][nt], 0, 0, 0);
    __syncthreads();
  }
  // epilogue
  #pragma unroll
  for (int mt = 0; mt < 4; ++mt) {
    int row = bm * 128 + wm * 64 + mt * 16 + quad * 4;
    #pragma unroll
    for (int nt = 0; nt < 2; ++nt) {
      int col = bn * 64 + wn * 32 + nt * 16 + l16;
      float bv = bias[col];
      #pragma unroll
      for (int r = 0; r < 4; ++r) {
        int rr = row + r;
        float v = acc[mt][nt][r] + bv;
        if (MODE == 2) {
          if (col < CDIM) {
            outf[(size_t)rr * CDIM + col] = v + resid[(size_t)rr * CDIM + col];
          }
        } else {
          outb[(size_t)rr * NPAD + col] = f2bf(v);
        }
      }
    }
  }
}

// ---------------- attention: per (window, head) ----------------
// kv_tok has 65537 rows; row 65536 is the bias row (for zero-padded positions)
__global__ __launch_bounds__(256) void attn_k(const ushort_t* __restrict__ q_tok,
    const ushort_t* __restrict__ kv_tok, ushort_t* __restrict__ ao)
{
  __shared__ __align__(16) ushort_t kS[32 * 40];
  __shared__ __align__(16) ushort_t vS[32 * 40];
  __shared__ __align__(16) ushort_t pS[256 * 40];
  const int w = blockIdx.x, h = blockIdx.y;
  const int tid = threadIdx.x;
  const int lane = tid & 63, wave = tid >> 6;
  const int quad = lane >> 4, l16 = lane & 15;
  const int wy = w >> 4, wx = w & 15;
  const int tok0 = wy * 16 * 256 + wx * 16;
  const int hc = h * 32;

  // persistent Q fragments (A layout): 4 m-tiles x 64 queries per wave
  bf16x8 qf[4];
  #pragma unroll
  for (int mt = 0; mt < 4; ++mt) {
    int qi = wave * 64 + mt * 16 + l16;
    int token = tok0 + (qi >> 4) * 256 + (qi & 15);
    qf[mt] = *reinterpret_cast<const bf16x8*>(q_tok + (size_t)token * CPAD + hc + quad * 8);
  }

  f32x4 o[4][2] = {};
  float mrun[4][4], lrun[4][4];
  #pragma unroll
  for (int mt = 0; mt < 4; ++mt)
    #pragma unroll
    for (int r = 0; r < 4; ++r) { mrun[mt][r] = -1e30f; lrun[mt][r] = 0.f; }

  const float scale = 0.18257418583505536f; // 1/sqrt(30)
  f32x4 zero = {0.f, 0.f, 0.f, 0.f};

  for (int c = 0; c < 18; ++c) {
    // gather K chunk [32 keys][32 dims]; V chunk transposed [32 dims][32 keys]
    {
      int isK = (tid < 128);
      int idx = isK ? tid : (tid - 128);
      int key = idx >> 2, seg = idx & 3;
      int p = c * 32 + key;              // 0..575 within the 24x24 patch
      int py = p / 24, px = p - py * 24;
      int y = wy * 16 - 4 + py;
      int xx = wx * 16 - 4 + px;
      int t = ((unsigned)y < 256u && (unsigned)xx < 256u) ? (y * 256 + xx) : NTOK;
      if (isK) {
        uint4 val = *reinterpret_cast<const uint4*>(kv_tok + (size_t)t * KVPAD + hc + seg * 8);
        *reinterpret_cast<uint4*>(&kS[key * 40 + seg * 8]) = val;
      } else {
        union { uint4 v; ushort_t s[8]; } u;
        u.v = *reinterpret_cast<const uint4*>(kv_tok + (size_t)t * KVPAD + 192 + hc + seg * 8);
        #pragma unroll
        for (int j = 0; j < 8; ++j) vS[(seg * 8 + j) * 40 + key] = u.s[j];
      }
    }
    __syncthreads();

    // S = Q K^T
    bf16x8 kf[2];
    #pragma unroll
    for (int nt = 0; nt < 2; ++nt)
      kf[nt] = *reinterpret_cast<const bf16x8*>(&kS[(nt * 16 + l16) * 40 + quad * 8]);
    f32x4 s[4][2];
    #pragma unroll
    for (int mt = 0; mt < 4; ++mt) {
      #pragma unroll
      for (int nt = 0; nt < 2; ++nt)
        s[mt][nt] = __builtin_amdgcn_mfma_f32_16x16x32_bf16(qf[mt], kf[nt], zero, 0, 0, 0);
      // online softmax: row = quad*4 + r, 32 cols spread over 16 lanes x 2 ntiles
      #pragma unroll
      for (int r = 0; r < 4; ++r) {
        float s0 = s[mt][0][r] * scale, s1 = s[mt][1][r] * scale;
        float cm = fmaxf(s0, s1);
        #pragma unroll
        for (int off = 1; off < 16; off <<= 1)
          cm = fmaxf(cm, __shfl_xor(cm, off, 64));
        float mnew = fmaxf(mrun[mt][r], cm);
        float alpha = __expf(mrun[mt][r] - mnew);
        float p0 = __expf(s0 - mnew), p1 = __expf(s1 - mnew);
        float rs = p0 + p1;
        #pragma unroll
        for (int off = 1; off < 16; off <<= 1)
          rs += __shfl_xor(rs, off, 64);
        lrun[mt][r] = lrun[mt][r] * alpha + rs;
        mrun[mt][r] = mnew;
        o[mt][0][r] *= alpha;
        o[mt][1][r] *= alpha;
        int prow = wave * 64 + mt * 16 + quad * 4 + r;
        pS[prow * 40 + l16] = f2bf(p0);
        pS[prow * 40 + 16 + l16] = f2bf(p1);
      }
    }
    // PV
    bf16x8 vf[2];
    #pragma unroll
    for (int dt = 0; dt < 2; ++dt)
      vf[dt] = *reinterpret_cast<const bf16x8*>(&vS[(dt * 16 + l16) * 40 + quad * 8]);
    #pragma unroll
    for (int mt = 0; mt < 4; ++mt) {
      bf16x8 pa = *reinterpret_cast<const bf16x8*>(&pS[(wave * 64 + mt * 16 + l16) * 40 + quad * 8]);
      #pragma unroll
      for (int dt = 0; dt < 2; ++dt)
        o[mt][dt] = __builtin_amdgcn_mfma_f32_16x16x32_bf16(pa, vf[dt], o[mt][dt], 0, 0, 0);
    }
    __syncthreads();
  }

  // epilogue: O /= l, scatter to ao[token][h*32 + d]
  #pragma unroll
  for (int mt = 0; mt < 4; ++mt) {
    #pragma unroll
    for (int r = 0; r < 4; ++r) {
      int qi = wave * 64 + mt * 16 + quad * 4 + r;
      int token = tok0 + (qi >> 4) * 256 + (qi & 15);
      float inv = 1.0f / lrun[mt][r];
      ao[(size_t)token * CPAD + hc + l16]      = f2bf(o[mt][0][r] * inv);
      ao[(size_t)token * CPAD + hc + 16 + l16] = f2bf(o[mt][1][r] * inv);
    }
  }
}

// ---------------- launch ----------------
extern "C" void kernel_launch(void* const* d_in, const int* in_sizes, int n_in,
                              void* d_out, int out_size, void* d_ws, size_t ws_size,
                              hipStream_t stream) {
  const float* x      = (const float*)d_in[0];
  const float* norm_w = (const float*)d_in[1];
  const float* norm_b = (const float*)d_in[2];
  const float* q_w    = (const float*)d_in[3];
  const float* q_b    = (const float*)d_in[4];
  const float* kv_w   = (const float*)d_in[5];
  const float* kv_b   = (const float*)d_in[6];
  const float* p_w    = (const float*)d_in[7];
  const float* p_b    = (const float*)d_in[8];

  char* base = (char*)d_ws;
  size_t off = 0;
  auto alloc = [&](size_t bytes) { char* p = base + off; off = (off + bytes + 255) & ~(size_t)255; return p; };
  ushort_t* xn_p   = (ushort_t*)alloc((size_t)NTOK * CPAD * 2);        // reused as ao
  ushort_t* q_tok  = (ushort_t*)alloc((size_t)NTOK * CPAD * 2);
  ushort_t* kv_tok = (ushort_t*)alloc((size_t)(NTOK + 1) * KVPAD * 2); // +1 bias row
  ushort_t* qwp   = (ushort_t*)alloc(192 * 192 * 2);
  ushort_t* kvwp  = (ushort_t*)alloc(192 * 384 * 2);
  ushort_t* pwp   = (ushort_t*)alloc(192 * 192 * 2);
  float* qbp  = (float*)alloc(192 * 4);
  float* kvbp = (float*)alloc(384 * 4);
  float* pbp  = (float*)alloc(192 * 4);
  ushort_t* ao = xn_p;  // alias: attention does not read xn_p

  prep_k<<<581, 256, 0, stream>>>(q_w, q_b, kv_w, kv_b, p_w, p_b,
                                  qwp, kvwp, pwp, qbp, kvbp, pbp,
                                  kv_tok + (size_t)NTOK * KVPAD);
  ln_k<<<NTOK / 4, 256, 0, stream>>>(x, norm_w, norm_b, xn_p);
  gemm_k<0><<<dim3(NTOK / 128, 3), 256, 0, stream>>>(xn_p, qwp, qbp, q_tok, nullptr, nullptr);
  gemm_k<1><<<dim3(NTOK / 128, 6), 256, 0, stream>>>(xn_p, kvwp, kvbp, kv_tok, nullptr, nullptr);
  attn_k<<<dim3(256, NHEAD), 256, 0, stream>>>(q_tok, kv_tok, ao);
  gemm_k<2><<<dim3(NTOK / 128, 3), 256, 0, stream>>>(ao, pwp, pbp, nullptr, (float*)d_out, x);
}

// Round 5
// 292.030 us; speedup vs baseline: 1.4082x; 1.4082x over previous
//
#include <hip/hip_runtime.h>
#include <math.h>

typedef __bf16 bf16x8 __attribute__((ext_vector_type(8)));
typedef float f32x4 __attribute__((ext_vector_type(4)));
typedef unsigned short ushort_t;

static __device__ __forceinline__ unsigned short f2bf(float f) {
  union { float f; unsigned int u; } c; c.f = f;
  unsigned int u = c.u;
  unsigned int r = u + 0x7FFFu + ((u >> 16) & 1u);
  return (unsigned short)(r >> 16);
}

// ---------------- constants ----------------
#define CDIM 180      // true channel dim
#define CPAD 192      // padded: 6 heads * 32
#define NTOK 65536
#define KVPAD 384     // k(192) | v(192)

// scale * log2(e) : p = exp2(s * SCL2E)
#define SCL2E 0.26339361f

// ---------------- prep: transpose/pad weights (f32 -> bf16) ----------------
// wqkvt[576][192] n-major (n<192: Q cols; n>=192: KV cols), pwt[192][192],
// qkvb[576], pbp[192], kv_bias_row[384].
// V pad-dim 30 bias = 1.0 -> ones-column for softmax row-sum l.
__global__ __launch_bounds__(256) void prep_k(
    const float* __restrict__ q_w, const float* __restrict__ q_b,
    const float* __restrict__ kv_w, const float* __restrict__ kv_b,
    const float* __restrict__ p_w, const float* __restrict__ p_b,
    ushort_t* __restrict__ wqkvt, ushort_t* __restrict__ pwt,
    float* __restrict__ qkvb, float* __restrict__ pbp,
    ushort_t* __restrict__ kv_bias_row)
{
  int i = blockIdx.x * 256 + threadIdx.x;
  if (i < 110592) { // wqkvt[n][k]
    int n = i / 192, k = i % 192;
    float v = 0.f;
    if (k < CDIM) {
      if (n < 192) { int h = n >> 5, d = n & 31; if (d < 30) v = q_w[k * CDIM + h * 30 + d]; }
      else { int cn = n - 192; int part = cn >= 192; int c2 = cn - part * 192;
             int h = c2 >> 5, d = c2 & 31;
             if (d < 30) v = kv_w[k * 360 + part * 180 + h * 30 + d]; }
    }
    wqkvt[i] = f2bf(v);
    return;
  }
  i -= 110592;
  if (i < 36864) { // pwt[n][r], r = (h,d)
    int n = i / 192, r = i % 192, h = r >> 5, d = r & 31;
    float v = (d < 30 && n < CDIM) ? p_w[(h * 30 + d) * CDIM + n] : 0.f;
    pwt[i] = f2bf(v);
    return;
  }
  i -= 36864;
  if (i < 576) {
    float v = 0.f;
    if (i < 192) { int h = i >> 5, d = i & 31; if (d < 30) v = q_b[h * 30 + d]; }
    else { int cn = i - 192; int part = cn >= 192; int c2 = cn - part * 192;
           int h = c2 >> 5, d = c2 & 31;
           if (d < 30) v = kv_b[part * 180 + h * 30 + d];
           else if (part == 1 && d == 30) v = 1.0f; }  // ones-column
    qkvb[i] = v;
    return;
  }
  i -= 576;
  if (i < 192) { pbp[i] = (i < CDIM) ? p_b[i] : 0.f; return; }
  i -= 192;
  if (i < 384) { // bias row for zero-padded window positions
    int part = i >= 192; int c2 = i - part * 192, h = c2 >> 5, d = c2 & 31;
    float v = 0.f;
    if (d < 30) v = kv_b[part * 180 + h * 30 + d];
    else if (part == 1 && d == 30) v = 1.0f;
    kv_bias_row[i] = f2bf(v);
    return;
  }
}

// ---------------- LayerNorm: x[65536][180] f32 -> xn_p[65536][192] bf16 ----------------
__global__ __launch_bounds__(256) void ln_k(const float* __restrict__ x,
    const float* __restrict__ nw, const float* __restrict__ nb,
    ushort_t* __restrict__ xn)
{
  const int lane = threadIdx.x & 63, wave = threadIdx.x >> 6;
  const int row = blockIdx.x * 4 + wave;
  const float* xr = x + (size_t)row * CDIM;
  float f0 = xr[lane];
  float f1 = xr[lane + 64];
  float f2 = (lane < 52) ? xr[lane + 128] : 0.f;
  float sum = f0 + f1 + f2;
  float sq = f0 * f0 + f1 * f1 + f2 * f2;
  #pragma unroll
  for (int off = 1; off < 64; off <<= 1) {
    sum += __shfl_xor(sum, off, 64);
    sq  += __shfl_xor(sq, off, 64);
  }
  const float inv_n = 1.0f / 180.0f;
  float mean = sum * inv_n;
  float var = sq * inv_n - mean * mean;
  float rs = rsqrtf(var + 1e-5f);
  ushort_t* xo = xn + (size_t)row * CPAD;
  #pragma unroll
  for (int e = 0; e < 3; ++e) {
    int col = lane + e * 64;
    float v = 0.f;
    if (col < CDIM) v = (( (e==0)?f0 : (e==1)?f1 : f2 ) - mean) * rs * nw[col] + nb[col];
    xo[col] = f2bf(v);
  }
}

// ---------------- fused GEMM: full A tile resident, n-tile loop ----------------
// MODE 0: A=xn_p, Wt=wqkvt (9 n-tiles): n<192 -> q_tok, else -> kv_tok
// MODE 1: A=ao,  Wt=pwt  (3 n-tiles): d_out f32 + residual x
template<int MODE>
__global__ __launch_bounds__(256) void gemm_k(const ushort_t* __restrict__ A,
    const ushort_t* __restrict__ Wt, const float* __restrict__ bias,
    ushort_t* __restrict__ q_out, ushort_t* __restrict__ kv_out,
    float* __restrict__ outf, const float* __restrict__ resid)
{
  constexpr int NT = (MODE == 0) ? 9 : 3;
  __shared__ __align__(16) ushort_t aS[128 * 200];
  __shared__ __align__(16) ushort_t bS[64 * 200];
  const int tid = threadIdx.x;
  const int lane = tid & 63, wave = tid >> 6;
  const int quad = lane >> 4, l16 = lane & 15;
  const int wm = wave & 1, wn = wave >> 1;
  const int bm = blockIdx.x;

  // stage full A tile: 128 rows x 192 cols (A row stride == 192, pads are zero)
  {
    const ushort_t* Ab = A + (size_t)bm * 128 * 192;
    #pragma unroll
    for (int it = 0; it < 12; ++it) {
      int f = it * 256 + tid;
      int row = f / 24, kq = f % 24;   // 24 x uint4 per row
      uint4 v = *reinterpret_cast<const uint4*>(Ab + row * 192 + kq * 8);
      *reinterpret_cast<uint4*>(&aS[row * 200 + kq * 8]) = v;
    }
  }

  for (int nt0 = 0; nt0 < NT; ++nt0) {
    __syncthreads();  // protects aS (first iter) and bS re-stage vs prior reads
    {
      const ushort_t* Wb = Wt + (size_t)nt0 * 64 * 192;
      #pragma unroll
      for (int it = 0; it < 6; ++it) {
        int f = it * 256 + tid;
        int row = f / 24, kq = f % 24;
        uint4 v = *reinterpret_cast<const uint4*>(Wb + row * 192 + kq * 8);
        *reinterpret_cast<uint4*>(&bS[row * 200 + kq * 8]) = v;
      }
    }
    __syncthreads();

    f32x4 acc[4][2] = {};
    #pragma unroll
    for (int ks = 0; ks < 6; ++ks) {
      bf16x8 af[4], bfr[2];
      #pragma unroll
      for (int mt = 0; mt < 4; ++mt)
        af[mt] = *reinterpret_cast<const bf16x8*>(&aS[(wm * 64 + mt * 16 + l16) * 200 + ks * 32 + quad * 8]);
      #pragma unroll
      for (int nt = 0; nt < 2; ++nt)
        bfr[nt] = *reinterpret_cast<const bf16x8*>(&bS[(wn * 32 + nt * 16 + l16) * 200 + ks * 32 + quad * 8]);
      #pragma unroll
      for (int mt = 0; mt < 4; ++mt)
        #pragma unroll
        for (int nt = 0; nt < 2; ++nt)
          acc[mt][nt] = __builtin_amdgcn_mfma_f32_16x16x32_bf16(af[mt], bfr[nt], acc[mt][nt], 0, 0, 0);
    }
    // epilogue for this n-tile
    #pragma unroll
    for (int mt = 0; mt < 4; ++mt) {
      int row = bm * 128 + wm * 64 + mt * 16 + quad * 4;
      #pragma unroll
      for (int nt = 0; nt < 2; ++nt) {
        int ncol = nt0 * 64 + wn * 32 + nt * 16 + l16;
        float bv = bias[ncol];
        #pragma unroll
        for (int r = 0; r < 4; ++r) {
          int rr = row + r;
          float v = acc[mt][nt][r] + bv;
          if (MODE == 0) {
            if (ncol < 192) q_out[(size_t)rr * CPAD + ncol] = f2bf(v);
            else kv_out[(size_t)rr * KVPAD + (ncol - 192)] = f2bf(v);
          } else {
            if (ncol < CDIM) outf[(size_t)rr * CDIM + ncol] = v + resid[(size_t)rr * CDIM + ncol];
          }
        }
      }
    }
  }
}

// ---------------- attention: per (window, head), 1 barrier/chunk ----------------
// kv_tok has 65537 rows; row 65536 = bias row (zero-padded positions).
// Fixed-max softmax (logits bounded); row-sum l via V ones-column (dim 30).
// pS/vT double-buffered: one __syncthreads() per chunk between LDS writes
// (V-transpose, P-store) and LDS reads (vf, pa). Cross-lane LDS traffic is
// never unsynchronized (round-4 NaN root cause).
__global__ __launch_bounds__(256) void attn_k(const ushort_t* __restrict__ q_tok,
    const ushort_t* __restrict__ kv_tok, ushort_t* __restrict__ ao)
{
  __shared__ __align__(16) ushort_t pS[2][256 * 40];
  __shared__ __align__(16) ushort_t vT[2][4][32 * 42];  // per-wave transposed V
  const int w = blockIdx.x, h = blockIdx.y;
  const int tid = threadIdx.x;
  const int lane = tid & 63, wave = tid >> 6;
  const int quad = lane >> 4, l16 = lane & 15;
  const int wy = w >> 4, wx = w & 15;
  const int tok0 = wy * 16 * 256 + wx * 16;
  const int hc = h * 32;

  // persistent Q fragments (A layout)
  bf16x8 qf[4];
  #pragma unroll
  for (int mt = 0; mt < 4; ++mt) {
    int qi = wave * 64 + mt * 16 + l16;
    int token = tok0 + (qi >> 4) * 256 + (qi & 15);
    qf[mt] = *reinterpret_cast<const bf16x8*>(q_tok + (size_t)token * CPAD + hc + quad * 8);
  }

  f32x4 o[4][2] = {};
  f32x4 zero = {0.f, 0.f, 0.f, 0.f};

  // V-staging geometry for this lane: key = lane>>1, dim-half = (lane&1)*16
  const int vkey = lane >> 1;
  const int vdh = (lane & 1) * 16;

  for (int c = 0; c < 18; ++c) {
    const int buf = c & 1;
    ushort_t* vTw = &vT[buf][wave][0];
    ushort_t* pSb = &pS[buf][0];
    const int kbase = c * 32;
    // ---- K fragments: direct global gather (B layout native)
    bf16x8 kf[2];
    #pragma unroll
    for (int nt = 0; nt < 2; ++nt) {
      int p = kbase + nt * 16 + l16;
      int py = p / 24, px = p - py * 24;
      int y = wy * 16 - 4 + py, xx = wx * 16 - 4 + px;
      int t = ((unsigned)y < 256u && (unsigned)xx < 256u) ? (y * 256 + xx) : NTOK;
      kf[nt] = *reinterpret_cast<const bf16x8*>(kv_tok + (size_t)t * KVPAD + hc + quad * 8);
    }
    // ---- stage V chunk transposed into this wave's own region
    {
      int p = kbase + vkey;
      int py = p / 24, px = p - py * 24;
      int y = wy * 16 - 4 + py, xx = wx * 16 - 4 + px;
      int t = ((unsigned)y < 256u && (unsigned)xx < 256u) ? (y * 256 + xx) : NTOK;
      const ushort_t* src = kv_tok + (size_t)t * KVPAD + 192 + hc + vdh;
      uint4 v0 = *reinterpret_cast<const uint4*>(src);
      uint4 v1 = *reinterpret_cast<const uint4*>(src + 8);
      unsigned vals[8] = {v0.x, v0.y, v0.z, v0.w, v1.x, v1.y, v1.z, v1.w};
      #pragma unroll
      for (int j2 = 0; j2 < 8; ++j2) {
        vTw[(vdh + j2 * 2    ) * 42 + vkey] = (ushort_t)(vals[j2] & 0xFFFFu);
        vTw[(vdh + j2 * 2 + 1) * 42 + vkey] = (ushort_t)(vals[j2] >> 16);
      }
    }
    // ---- S = Q K^T
    f32x4 s[4][2];
    #pragma unroll
    for (int mt = 0; mt < 4; ++mt)
      #pragma unroll
      for (int nt = 0; nt < 2; ++nt)
        s[mt][nt] = __builtin_amdgcn_mfma_f32_16x16x32_bf16(qf[mt], kf[nt], zero, 0, 0, 0);
    // ---- elementwise softmax numerator -> pS (bf16, round-nearest store)
    #pragma unroll
    for (int mt = 0; mt < 4; ++mt) {
      #pragma unroll
      for (int r = 0; r < 4; ++r) {
        int prow = wave * 64 + mt * 16 + quad * 4 + r;
        #pragma unroll
        for (int nt = 0; nt < 2; ++nt) {
          float pv = exp2f(s[mt][nt][r] * SCL2E);
          union { float f; unsigned u; } cv; cv.f = pv;
          unsigned rr = cv.u + 0x8000u;
          pSb[prow * 40 + nt * 16 + l16] = (ushort_t)(rr >> 16);
        }
      }
    }

    __syncthreads();  // all LDS writes (vT, pS) done before any reads

    // ---- PV
    bf16x8 vf[2];
    #pragma unroll
    for (int dt = 0; dt < 2; ++dt) {
      const unsigned* vp = reinterpret_cast<const unsigned*>(&vTw[(dt * 16 + l16) * 42 + quad * 8]);
      union { unsigned u[4]; bf16x8 v; } asm_;
      asm_.u[0] = vp[0]; asm_.u[1] = vp[1]; asm_.u[2] = vp[2]; asm_.u[3] = vp[3];
      vf[dt] = asm_.v;
    }
    #pragma unroll
    for (int mt = 0; mt < 4; ++mt) {
      bf16x8 pa = *reinterpret_cast<const bf16x8*>(&pSb[(wave * 64 + mt * 16 + l16) * 40 + quad * 8]);
      #pragma unroll
      for (int dt = 0; dt < 2; ++dt)
        o[mt][dt] = __builtin_amdgcn_mfma_f32_16x16x32_bf16(pa, vf[dt], o[mt][dt], 0, 0, 0);
    }
  }

  // ---- epilogue: l = O[:,30] (ones-column), O /= l, scatter
  #pragma unroll
  for (int mt = 0; mt < 4; ++mt) {
    #pragma unroll
    for (int r = 0; r < 4; ++r) {
      float l = __shfl(o[mt][1][r], (lane & 48) + 14, 64);
      float inv = 1.0f / l;
      int qi = wave * 64 + mt * 16 + quad * 4 + r;
      int token = tok0 + (qi >> 4) * 256 + (qi & 15);
      ao[(size_t)token * CPAD + hc + l16]      = f2bf(o[mt][0][r] * inv);
      ao[(size_t)token * CPAD + hc + 16 + l16] = f2bf(o[mt][1][r] * inv);
    }
  }
}

// ---------------- launch ----------------
extern "C" void kernel_launch(void* const* d_in, const int* in_sizes, int n_in,
                              void* d_out, int out_size, void* d_ws, size_t ws_size,
                              hipStream_t stream) {
  const float* x      = (const float*)d_in[0];
  const float* norm_w = (const float*)d_in[1];
  const float* norm_b = (const float*)d_in[2];
  const float* q_w    = (const float*)d_in[3];
  const float* q_b    = (const float*)d_in[4];
  const float* kv_w   = (const float*)d_in[5];
  const float* kv_b   = (const float*)d_in[6];
  const float* p_w    = (const float*)d_in[7];
  const float* p_b    = (const float*)d_in[8];

  char* base = (char*)d_ws;
  size_t off = 0;
  auto alloc = [&](size_t bytes) { char* p = base + off; off = (off + bytes + 255) & ~(size_t)255; return p; };
  ushort_t* xn_p   = (ushort_t*)alloc((size_t)NTOK * CPAD * 2);        // reused as ao
  ushort_t* q_tok  = (ushort_t*)alloc((size_t)NTOK * CPAD * 2);
  ushort_t* kv_tok = (ushort_t*)alloc((size_t)(NTOK + 1) * KVPAD * 2); // +1 bias row
  ushort_t* wqkvt  = (ushort_t*)alloc(576 * 192 * 2);
  ushort_t* pwt    = (ushort_t*)alloc(192 * 192 * 2);
  float* qkvb = (float*)alloc(576 * 4);
  float* pbp  = (float*)alloc(192 * 4);
  ushort_t* ao = xn_p;  // alias: attention does not read xn_p

  prep_k<<<581, 256, 0, stream>>>(q_w, q_b, kv_w, kv_b, p_w, p_b,
                                  wqkvt, pwt, qkvb, pbp,
                                  kv_tok + (size_t)NTOK * KVPAD);
  ln_k<<<NTOK / 4, 256, 0, stream>>>(x, norm_w, norm_b, xn_p);
  gemm_k<0><<<NTOK / 128, 256, 0, stream>>>(xn_p, wqkvt, qkvb, q_tok, kv_tok, nullptr, nullptr);
  attn_k<<<dim3(256, 6), 256, 0, stream>>>(q_tok, kv_tok, ao);
  gemm_k<1><<<NTOK / 128, 256, 0, stream>>>(ao, pwt, pbp, nullptr, nullptr, (float*)d_out, x);
}

// Round 6
// 281.154 us; speedup vs baseline: 1.4627x; 1.0387x over previous
//
#include <hip/hip_runtime.h>
#include <math.h>

typedef __bf16 bf16x8 __attribute__((ext_vector_type(8)));
typedef float f32x4 __attribute__((ext_vector_type(4)));
typedef unsigned short ushort_t;

static __device__ __forceinline__ unsigned short f2bf(float f) {
  union { float f; unsigned int u; } c; c.f = f;
  unsigned int u = c.u;
  unsigned int r = u + 0x7FFFu + ((u >> 16) & 1u);
  return (unsigned short)(r >> 16);
}

// ---------------- constants ----------------
#define CDIM 180      // true channel dim
#define CPAD 192      // padded: 6 heads * 32
#define NTOK 65536

// scale * log2(e) : p = exp2(s * SCL2E)
#define SCL2E 0.26339361f

// pack two f32's high halves into packed bf16 pair (truncating):
// D = {hi16(b), hi16(a)}
static __device__ __forceinline__ unsigned pk_bf(float a, float b) {
  union { float f; unsigned u; } ca, cb; ca.f = a; cb.f = b;
  return __builtin_amdgcn_perm(cb.u, ca.u, 0x07060302u);
}

// ---------------- prep: transpose/pad weights (f32 -> bf16) ----------------
// wqkvt[576][192] n-major (n<192: Q; 192..383: K; 384..575: V), pwt[192][192],
// qkvb[576], pbp[192], k_bias_row[192], vbias[192] (dup-packed bf16 u32).
// V pad-dim 30 bias = 1.0 -> ones-column gives softmax row-sum l via PV MFMA.
__global__ __launch_bounds__(256) void prep_k(
    const float* __restrict__ q_w, const float* __restrict__ q_b,
    const float* __restrict__ kv_w, const float* __restrict__ kv_b,
    const float* __restrict__ p_w, const float* __restrict__ p_b,
    ushort_t* __restrict__ wqkvt, ushort_t* __restrict__ pwt,
    float* __restrict__ qkvb, float* __restrict__ pbp,
    ushort_t* __restrict__ k_bias_row, unsigned* __restrict__ vbias)
{
  int i = blockIdx.x * 256 + threadIdx.x;
  if (i < 110592) { // wqkvt[n][k]
    int n = i / 192, k = i % 192;
    float v = 0.f;
    if (k < CDIM) {
      if (n < 192) { int h = n >> 5, d = n & 31; if (d < 30) v = q_w[k * CDIM + h * 30 + d]; }
      else { int cn = n - 192; int part = cn >= 192; int c2 = cn - part * 192;
             int h = c2 >> 5, d = c2 & 31;
             if (d < 30) v = kv_w[k * 360 + part * 180 + h * 30 + d]; }
    }
    wqkvt[i] = f2bf(v);
    return;
  }
  i -= 110592;
  if (i < 36864) { // pwt[n][r], r = (h,d)
    int n = i / 192, r = i % 192, h = r >> 5, d = r & 31;
    float v = (d < 30 && n < CDIM) ? p_w[(h * 30 + d) * CDIM + n] : 0.f;
    pwt[i] = f2bf(v);
    return;
  }
  i -= 36864;
  if (i < 576) {
    float v = 0.f;
    if (i < 192) { int h = i >> 5, d = i & 31; if (d < 30) v = q_b[h * 30 + d]; }
    else { int cn = i - 192; int part = cn >= 192; int c2 = cn - part * 192;
           int h = c2 >> 5, d = c2 & 31;
           if (d < 30) v = kv_b[part * 180 + h * 30 + d];
           else if (part == 1 && d == 30) v = 1.0f; }  // ones-column
    qkvb[i] = v;
    return;
  }
  i -= 576;
  if (i < 192) { pbp[i] = (i < CDIM) ? p_b[i] : 0.f; return; }
  i -= 192;
  if (i < 192) { // K bias row (zero-padded positions: xn==0 -> k = bias)
    int h = i >> 5, d = i & 31;
    k_bias_row[i] = (d < 30) ? f2bf(kv_b[h * 30 + d]) : (ushort_t)0;
    return;
  }
  i -= 192;
  if (i < 192) { // V bias, dup-packed (for OOB splat in attn)
    int h = i >> 5, d = i & 31;
    float v = 0.f;
    if (d < 30) v = kv_b[180 + h * 30 + d];
    else if (d == 30) v = 1.0f;
    unsigned b = f2bf(v);
    vbias[i] = b | (b << 16);
    return;
  }
}

// ---------------- LayerNorm: x[65536][180] f32 -> xn_p[65536][192] bf16 ----------------
__global__ __launch_bounds__(256) void ln_k(const float* __restrict__ x,
    const float* __restrict__ nw, const float* __restrict__ nb,
    ushort_t* __restrict__ xn)
{
  const int lane = threadIdx.x & 63, wave = threadIdx.x >> 6;
  const int row = blockIdx.x * 4 + wave;
  const float* xr = x + (size_t)row * CDIM;
  float f0 = xr[lane];
  float f1 = xr[lane + 64];
  float f2 = (lane < 52) ? xr[lane + 128] : 0.f;
  float sum = f0 + f1 + f2;
  float sq = f0 * f0 + f1 * f1 + f2 * f2;
  #pragma unroll
  for (int off = 1; off < 64; off <<= 1) {
    sum += __shfl_xor(sum, off, 64);
    sq  += __shfl_xor(sq, off, 64);
  }
  const float inv_n = 1.0f / 180.0f;
  float mean = sum * inv_n;
  float var = sq * inv_n - mean * mean;
  float rs = rsqrtf(var + 1e-5f);
  ushort_t* xo = xn + (size_t)row * CPAD;
  #pragma unroll
  for (int e = 0; e < 3; ++e) {
    int col = lane + e * 64;
    float v = 0.f;
    if (col < CDIM) v = (( (e==0)?f0 : (e==1)?f1 : f2 ) - mean) * rs * nw[col] + nb[col];
    xo[col] = f2bf(v);
  }
}

// ---------------- fused GEMM: full A tile resident, n-tile loop ----------------
// MODE 0: A=xn_p, Wt=wqkvt (9 n-tiles): n<192 -> q_tok; 192..383 -> k_tok;
//         384..575 -> vt (token-major per dim, packed b64 stores)
// MODE 1: A=ao,  Wt=pwt  (3 n-tiles): d_out f32 + residual x
template<int MODE>
__global__ __launch_bounds__(256) void gemm_k(const ushort_t* __restrict__ A,
    const ushort_t* __restrict__ Wt, const float* __restrict__ bias,
    ushort_t* __restrict__ q_out, ushort_t* __restrict__ k_out,
    ushort_t* __restrict__ vt_out,
    float* __restrict__ outf, const float* __restrict__ resid)
{
  constexpr int NT = (MODE == 0) ? 9 : 3;
  __shared__ __align__(16) ushort_t aS[128 * 200];
  __shared__ __align__(16) ushort_t bS[64 * 200];
  const int tid = threadIdx.x;
  const int lane = tid & 63, wave = tid >> 6;
  const int quad = lane >> 4, l16 = lane & 15;
  const int wm = wave & 1, wn = wave >> 1;
  const int bm = blockIdx.x;

  // stage full A tile: 128 rows x 192 cols
  {
    const ushort_t* Ab = A + (size_t)bm * 128 * 192;
    #pragma unroll
    for (int it = 0; it < 12; ++it) {
      int f = it * 256 + tid;
      int row = f / 24, kq = f % 24;
      uint4 v = *reinterpret_cast<const uint4*>(Ab + row * 192 + kq * 8);
      *reinterpret_cast<uint4*>(&aS[row * 200 + kq * 8]) = v;
    }
  }

  for (int nt0 = 0; nt0 < NT; ++nt0) {
    __syncthreads();
    {
      const ushort_t* Wb = Wt + (size_t)nt0 * 64 * 192;
      #pragma unroll
      for (int it = 0; it < 6; ++it) {
        int f = it * 256 + tid;
        int row = f / 24, kq = f % 24;
        uint4 v = *reinterpret_cast<const uint4*>(Wb + row * 192 + kq * 8);
        *reinterpret_cast<uint4*>(&bS[row * 200 + kq * 8]) = v;
      }
    }
    __syncthreads();

    f32x4 acc[4][2] = {};
    #pragma unroll
    for (int ks = 0; ks < 6; ++ks) {
      bf16x8 af[4], bfr[2];
      #pragma unroll
      for (int mt = 0; mt < 4; ++mt)
        af[mt] = *reinterpret_cast<const bf16x8*>(&aS[(wm * 64 + mt * 16 + l16) * 200 + ks * 32 + quad * 8]);
      #pragma unroll
      for (int nt = 0; nt < 2; ++nt)
        bfr[nt] = *reinterpret_cast<const bf16x8*>(&bS[(wn * 32 + nt * 16 + l16) * 200 + ks * 32 + quad * 8]);
      #pragma unroll
      for (int mt = 0; mt < 4; ++mt)
        #pragma unroll
        for (int nt = 0; nt < 2; ++nt)
          acc[mt][nt] = __builtin_amdgcn_mfma_f32_16x16x32_bf16(af[mt], bfr[nt], acc[mt][nt], 0, 0, 0);
    }
    // epilogue for this n-tile
    #pragma unroll
    for (int mt = 0; mt < 4; ++mt) {
      int row = bm * 128 + wm * 64 + mt * 16 + quad * 4;
      #pragma unroll
      for (int nt = 0; nt < 2; ++nt) {
        int ncol = nt0 * 64 + wn * 32 + nt * 16 + l16;
        float bv = bias[ncol];
        if (MODE == 0 && nt0 >= 6) {
          // V part: 4 consecutive tokens for one dim -> packed 8B store
          int d = ncol - 384;
          unsigned p0 = pk_bf(acc[mt][nt][0] + bv, acc[mt][nt][1] + bv);
          unsigned p1 = pk_bf(acc[mt][nt][2] + bv, acc[mt][nt][3] + bv);
          uint2 val; val.x = p0; val.y = p1;
          *reinterpret_cast<uint2*>(vt_out + (size_t)d * NTOK + row) = val;
        } else {
          #pragma unroll
          for (int r = 0; r < 4; ++r) {
            int rr = row + r;
            float v = acc[mt][nt][r] + bv;
            if (MODE == 0) {
              if (ncol < 192) q_out[(size_t)rr * CPAD + ncol] = f2bf(v);
              else k_out[(size_t)rr * CPAD + (ncol - 192)] = f2bf(v);
            } else {
              if (ncol < CDIM) outf[(size_t)rr * CDIM + ncol] = v + resid[(size_t)rr * CDIM + ncol];
            }
          }
        }
      }
    }
  }
}

// ---------------- attention: per (window, head) — ZERO LDS, zero barriers ----
// S^T = K·Q^T (A=K, B=Q). C-layout of S^T == A-layout of PV MFMA under the
// key permutation key(kt, m) = 8*(m>>2) + 4*kt + (m&3). V is pre-transposed
// in global (vt[192][65536]); PV B-frags are 8B loads of 4 consecutive
// tokens (4-aligned patch groups stay within one patch row; uniform OOB).
// Fixed-max softmax; row-sum l via V ones-column (dim 30).
__global__ __launch_bounds__(256) void attn_k(const ushort_t* __restrict__ q_tok,
    const ushort_t* __restrict__ k_tok, const ushort_t* __restrict__ vt,
    const unsigned* __restrict__ vbias, ushort_t* __restrict__ ao)
{
  const int w = blockIdx.x, h = blockIdx.y;
  const int tid = threadIdx.x;
  const int lane = tid & 63, wave = tid >> 6;
  const int quad = lane >> 4, l16 = lane & 15;
  const int wy = w >> 4, wx = w & 15;
  const int tok0 = wy * 16 * 256 + wx * 16;
  const int hc = h * 32;

  // Q fragments (B-operand layout), 4 q-tiles of 16
  bf16x8 qf[4];
  #pragma unroll
  for (int qt = 0; qt < 4; ++qt) {
    int qi = wave * 64 + qt * 16 + l16;
    int token = tok0 + (qi >> 4) * 256 + (qi & 15);
    qf[qt] = *reinterpret_cast<const bf16x8*>(q_tok + (size_t)token * CPAD + hc + quad * 8);
  }

  // permuted key id for the K A-frag gather (kt adds 4)
  const int key0 = ((l16 >> 2) << 3) + (l16 & 3);
  // V bias splats for OOB groups
  const unsigned vs[2] = { vbias[hc + l16], vbias[hc + 16 + l16] };

  f32x4 o[4][2] = {};
  f32x4 zero = {0.f, 0.f, 0.f, 0.f};

  for (int c = 0; c < 18; ++c) {
    const int pbase = c * 32;
    // ---- K A-frags: direct global gather (per-lane 16B)
    bf16x8 kf[2];
    #pragma unroll
    for (int kt = 0; kt < 2; ++kt) {
      int p = pbase + key0 + kt * 4;
      int py = p / 24, px = p - py * 24;
      int y = wy * 16 - 4 + py, xx = wx * 16 - 4 + px;
      int t = ((unsigned)y < 256u && (unsigned)xx < 256u) ? (y * 256 + xx) : NTOK;
      kf[kt] = *reinterpret_cast<const bf16x8*>(k_tok + (size_t)t * CPAD + hc + quad * 8);
    }
    // ---- V B-frags: two 8B loads per dt (4-token groups), OOB -> bias splat
    unsigned vv[2][4];
    #pragma unroll
    for (int h2 = 0; h2 < 2; ++h2) {
      int p0 = pbase + quad * 8 + h2 * 4;
      int py = p0 / 24, px0 = p0 - py * 24;
      int y = wy * 16 - 4 + py, xx0 = wx * 16 - 4 + px0;
      bool inb = ((unsigned)y < 256u) && ((unsigned)xx0 < 256u);
      int tok = inb ? (y * 256 + xx0) : 0;
      #pragma unroll
      for (int dt = 0; dt < 2; ++dt) {
        uint2 val = *reinterpret_cast<const uint2*>(vt + (size_t)(hc + dt * 16 + l16) * NTOK + tok);
        vv[dt][h2 * 2]     = inb ? val.x : vs[dt];
        vv[dt][h2 * 2 + 1] = inb ? val.y : vs[dt];
      }
    }
    bf16x8 vf[2];
    #pragma unroll
    for (int dt = 0; dt < 2; ++dt) {
      union { unsigned u[4]; bf16x8 v; } asm_;
      asm_.u[0] = vv[dt][0]; asm_.u[1] = vv[dt][1];
      asm_.u[2] = vv[dt][2]; asm_.u[3] = vv[dt][3];
      vf[dt] = asm_.v;
    }
    // ---- S^T = K Q^T, exp, pack P directly in registers (A-layout)
    bf16x8 pa[4];
    #pragma unroll
    for (int qt = 0; qt < 4; ++qt) {
      f32x4 s0 = __builtin_amdgcn_mfma_f32_16x16x32_bf16(kf[0], qf[qt], zero, 0, 0, 0);
      f32x4 s1 = __builtin_amdgcn_mfma_f32_16x16x32_bf16(kf[1], qf[qt], zero, 0, 0, 0);
      float e0 = exp2f(s0[0] * SCL2E), e1 = exp2f(s0[1] * SCL2E);
      float e2 = exp2f(s0[2] * SCL2E), e3 = exp2f(s0[3] * SCL2E);
      float e4 = exp2f(s1[0] * SCL2E), e5 = exp2f(s1[1] * SCL2E);
      float e6 = exp2f(s1[2] * SCL2E), e7 = exp2f(s1[3] * SCL2E);
      union { unsigned u[4]; bf16x8 v; } pk;
      pk.u[0] = pk_bf(e0, e1); pk.u[1] = pk_bf(e2, e3);
      pk.u[2] = pk_bf(e4, e5); pk.u[3] = pk_bf(e6, e7);
      pa[qt] = pk.v;
    }
    // ---- PV (K=32 over the chunk's 32 keys)
    #pragma unroll
    for (int qt = 0; qt < 4; ++qt)
      #pragma unroll
      for (int dt = 0; dt < 2; ++dt)
        o[qt][dt] = __builtin_amdgcn_mfma_f32_16x16x32_bf16(pa[qt], vf[dt], o[qt][dt], 0, 0, 0);
  }

  // ---- epilogue: l = O[:,30] (ones-column), O /= l, scatter
  #pragma unroll
  for (int qt = 0; qt < 4; ++qt) {
    #pragma unroll
    for (int r = 0; r < 4; ++r) {
      float l = __shfl(o[qt][1][r], (lane & 48) + 14, 64);
      float inv = 1.0f / l;
      int qi = wave * 64 + qt * 16 + quad * 4 + r;
      int token = tok0 + (qi >> 4) * 256 + (qi & 15);
      ao[(size_t)token * CPAD + hc + l16]      = f2bf(o[qt][0][r] * inv);
      ao[(size_t)token * CPAD + hc + 16 + l16] = f2bf(o[qt][1][r] * inv);
    }
  }
}

// ---------------- launch ----------------
extern "C" void kernel_launch(void* const* d_in, const int* in_sizes, int n_in,
                              void* d_out, int out_size, void* d_ws, size_t ws_size,
                              hipStream_t stream) {
  const float* x      = (const float*)d_in[0];
  const float* norm_w = (const float*)d_in[1];
  const float* norm_b = (const float*)d_in[2];
  const float* q_w    = (const float*)d_in[3];
  const float* q_b    = (const float*)d_in[4];
  const float* kv_w   = (const float*)d_in[5];
  const float* kv_b   = (const float*)d_in[6];
  const float* p_w    = (const float*)d_in[7];
  const float* p_b    = (const float*)d_in[8];

  char* base = (char*)d_ws;
  size_t off = 0;
  auto alloc = [&](size_t bytes) { char* p = base + off; off = (off + bytes + 255) & ~(size_t)255; return p; };
  ushort_t* xn_p  = (ushort_t*)alloc((size_t)NTOK * CPAD * 2);        // reused as ao
  ushort_t* q_tok = (ushort_t*)alloc((size_t)NTOK * CPAD * 2);
  ushort_t* k_tok = (ushort_t*)alloc((size_t)(NTOK + 1) * CPAD * 2);  // +1 bias row
  ushort_t* vt    = (ushort_t*)alloc((size_t)CPAD * NTOK * 2);        // V transposed [d][token]
  ushort_t* wqkvt = (ushort_t*)alloc(576 * 192 * 2);
  ushort_t* pwt   = (ushort_t*)alloc(192 * 192 * 2);
  float* qkvb = (float*)alloc(576 * 4);
  float* pbp  = (float*)alloc(192 * 4);
  unsigned* vbias = (unsigned*)alloc(192 * 4);
  ushort_t* ao = xn_p;  // alias: attention does not read xn_p

  prep_k<<<581, 256, 0, stream>>>(q_w, q_b, kv_w, kv_b, p_w, p_b,
                                  wqkvt, pwt, qkvb, pbp,
                                  k_tok + (size_t)NTOK * CPAD, vbias);
  ln_k<<<NTOK / 4, 256, 0, stream>>>(x, norm_w, norm_b, xn_p);
  gemm_k<0><<<NTOK / 128, 256, 0, stream>>>(xn_p, wqkvt, qkvb, q_tok, k_tok, vt, nullptr, nullptr);
  attn_k<<<dim3(256, 6), 256, 0, stream>>>(q_tok, k_tok, vt, vbias, ao);
  gemm_k<1><<<NTOK / 128, 256, 0, stream>>>(ao, pwt, pbp, nullptr, nullptr, nullptr, (float*)d_out, x);
}

// Round 7
// 239.762 us; speedup vs baseline: 1.7152x; 1.1726x over previous
//
#include <hip/hip_runtime.h>
#include <math.h>

typedef __bf16 bf16x8 __attribute__((ext_vector_type(8)));
typedef float f32x4 __attribute__((ext_vector_type(4)));
typedef unsigned short ushort_t;

static __device__ __forceinline__ unsigned short f2bf(float f) {
  union { float f; unsigned int u; } c; c.f = f;
  unsigned int u = c.u;
  unsigned int r = u + 0x7FFFu + ((u >> 16) & 1u);
  return (unsigned short)(r >> 16);
}

// ---------------- constants ----------------
#define CDIM 180      // true channel dim
#define CPAD 192      // padded: 6 heads * 32
#define NTOK 65536

// scale * log2(e), folded into Q weights/bias at prep: p = exp2(S)
#define SCL2E 0.26339361f

// pack two f32's high halves into packed bf16 pair (truncating): D = {hi16(b), hi16(a)}
static __device__ __forceinline__ unsigned pk_bf(float a, float b) {
  union { float f; unsigned u; } ca, cb; ca.f = a; cb.f = b;
  return __builtin_amdgcn_perm(cb.u, ca.u, 0x07060302u);
}

// ---------------- prep ----------------
// wqkvt[576][192] n-major (n<192: Q *SCL2E; 192..383: K; 384..575: V),
// pwt[192][192] n-major, qkvb[576] (Q part *SCL2E), pbp[192],
// k_bias_row[192] (-> k_tok row NTOK), vt4 bias group (tok NTOK).
__global__ __launch_bounds__(256) void prep_k(
    const float* __restrict__ q_w, const float* __restrict__ q_b,
    const float* __restrict__ kv_w, const float* __restrict__ kv_b,
    const float* __restrict__ p_w, const float* __restrict__ p_b,
    ushort_t* __restrict__ wqkvt, ushort_t* __restrict__ pwt,
    float* __restrict__ qkvb, float* __restrict__ pbp,
    ushort_t* __restrict__ k_bias_row, ushort_t* __restrict__ vt4_bias_grp)
{
  int i = blockIdx.x * 256 + threadIdx.x;
  if (i < 110592) { // wqkvt[n][k]
    int n = i / 192, k = i % 192;
    float v = 0.f;
    if (k < CDIM) {
      if (n < 192) { int h = n >> 5, d = n & 31; if (d < 30) v = q_w[k * CDIM + h * 30 + d] * SCL2E; }
      else { int cn = n - 192; int part = cn >= 192; int c2 = cn - part * 192;
             int h = c2 >> 5, d = c2 & 31;
             if (d < 30) v = kv_w[k * 360 + part * 180 + h * 30 + d]; }
    }
    wqkvt[i] = f2bf(v);
    return;
  }
  i -= 110592;
  if (i < 36864) { // pwt[n][r], r = (h,d)
    int n = i / 192, r = i % 192, h = r >> 5, d = r & 31;
    float v = (d < 30 && n < CDIM) ? p_w[(h * 30 + d) * CDIM + n] : 0.f;
    pwt[i] = f2bf(v);
    return;
  }
  i -= 36864;
  if (i < 576) {
    float v = 0.f;
    if (i < 192) { int h = i >> 5, d = i & 31; if (d < 30) v = q_b[h * 30 + d] * SCL2E; }
    else { int cn = i - 192; int part = cn >= 192; int c2 = cn - part * 192;
           int h = c2 >> 5, d = c2 & 31;
           if (d < 30) v = kv_b[part * 180 + h * 30 + d];
           else if (part == 1 && d == 30) v = 1.0f; }  // ones-column -> row-sum l
    qkvb[i] = v;
    return;
  }
  i -= 576;
  if (i < 192) { pbp[i] = (i < CDIM) ? p_b[i] : 0.f; return; }
  i -= 192;
  if (i < 192) { // K bias row (zero-padded positions: xn==0 -> k = bias)
    int h = i >> 5, d = i & 31;
    k_bias_row[i] = (d < 30) ? f2bf(kv_b[h * 30 + d]) : (ushort_t)0;
    return;
  }
  i -= 192;
  if (i < 768) { // vt4 bias group at tok==NTOK: [192 d][4]
    int d = i >> 2, h = d >> 5, dd = d & 31;
    float v = 0.f;
    if (dd < 30) v = kv_b[180 + h * 30 + dd];
    else if (dd == 30) v = 1.0f;
    vt4_bias_grp[i] = f2bf(v);
    return;
  }
}

// ---------------- LayerNorm: x[65536][180] f32 -> xn_p[65536][192] bf16 ----------------
__global__ __launch_bounds__(256) void ln_k(const float* __restrict__ x,
    const float* __restrict__ nw, const float* __restrict__ nb,
    ushort_t* __restrict__ xn)
{
  const int lane = threadIdx.x & 63, wave = threadIdx.x >> 6;
  const int row = blockIdx.x * 4 + wave;
  const float* xr = x + (size_t)row * CDIM;
  float f0 = xr[lane];
  float f1 = xr[lane + 64];
  float f2 = (lane < 52) ? xr[lane + 128] : 0.f;
  float sum = f0 + f1 + f2;
  float sq = f0 * f0 + f1 * f1 + f2 * f2;
  #pragma unroll
  for (int off = 1; off < 64; off <<= 1) {
    sum += __shfl_xor(sum, off, 64);
    sq  += __shfl_xor(sq, off, 64);
  }
  const float inv_n = 1.0f / 180.0f;
  float mean = sum * inv_n;
  float var = sq * inv_n - mean * mean;
  float rs = rsqrtf(var + 1e-5f);
  ushort_t* xo = xn + (size_t)row * CPAD;
  #pragma unroll
  for (int e = 0; e < 3; ++e) {
    int col = lane + e * 64;
    float v = 0.f;
    if (col < CDIM) v = (( (e==0)?f0 : (e==1)?f1 : f2 ) - mean) * rs * nw[col] + nb[col];
    xo[col] = f2bf(v);
  }
}

// ---------------- fused GEMM: A tile in LDS (1 barrier), B global-direct ----
// MODE 0: A=xn_p, Wt=wqkvt (9 n-tiles): n<192 -> q_tok; 192..383 -> k_tok;
//         384..575 -> vt4 (group-of-4-token layout, packed 8B stores)
// MODE 1: A=ao,  Wt=pwt  (3 n-tiles): d_out f32 + residual x
template<int MODE>
__global__ __launch_bounds__(256) void gemm_k(const ushort_t* __restrict__ A,
    const ushort_t* __restrict__ Wt, const float* __restrict__ bias,
    ushort_t* __restrict__ q_out, ushort_t* __restrict__ k_out,
    ushort_t* __restrict__ vt_out,
    float* __restrict__ outf, const float* __restrict__ resid)
{
  constexpr int NT = (MODE == 0) ? 9 : 3;
  __shared__ __align__(16) ushort_t aS[128 * 200];
  const int tid = threadIdx.x;
  const int lane = tid & 63, wave = tid >> 6;
  const int quad = lane >> 4, l16 = lane & 15;
  const int wm = wave & 1, wn = wave >> 1;
  const int bm = blockIdx.x;

  // stage full A tile: 128 rows x 192 cols
  {
    const ushort_t* Ab = A + (size_t)bm * 128 * 192;
    #pragma unroll
    for (int it = 0; it < 12; ++it) {
      int f = it * 256 + tid;
      int row = f / 24, kq = f % 24;
      uint4 v = *reinterpret_cast<const uint4*>(Ab + row * 192 + kq * 8);
      *reinterpret_cast<uint4*>(&aS[row * 200 + kq * 8]) = v;
    }
  }
  __syncthreads();  // the only barrier

  for (int nt0 = 0; nt0 < NT; ++nt0) {
    f32x4 acc[4][2] = {};
    #pragma unroll
    for (int ks = 0; ks < 6; ++ks) {
      bf16x8 af[4], bfr[2];
      #pragma unroll
      for (int nt = 0; nt < 2; ++nt) {
        int n = nt0 * 64 + wn * 32 + nt * 16 + l16;
        bfr[nt] = *reinterpret_cast<const bf16x8*>(Wt + (size_t)n * 192 + ks * 32 + quad * 8);
      }
      #pragma unroll
      for (int mt = 0; mt < 4; ++mt)
        af[mt] = *reinterpret_cast<const bf16x8*>(&aS[(wm * 64 + mt * 16 + l16) * 200 + ks * 32 + quad * 8]);
      #pragma unroll
      for (int mt = 0; mt < 4; ++mt)
        #pragma unroll
        for (int nt = 0; nt < 2; ++nt)
          acc[mt][nt] = __builtin_amdgcn_mfma_f32_16x16x32_bf16(af[mt], bfr[nt], acc[mt][nt], 0, 0, 0);
    }
    // epilogue for this n-tile
    #pragma unroll
    for (int mt = 0; mt < 4; ++mt) {
      int row = bm * 128 + wm * 64 + mt * 16 + quad * 4;
      #pragma unroll
      for (int nt = 0; nt < 2; ++nt) {
        int ncol = nt0 * 64 + wn * 32 + nt * 16 + l16;
        float bv = bias[ncol];
        if (MODE == 0 && nt0 >= 6) {
          // V part: 4 consecutive tokens (row..row+3, row%4==0) for dim d
          int d = ncol - 384;
          unsigned p0 = pk_bf(acc[mt][nt][0] + bv, acc[mt][nt][1] + bv);
          unsigned p1 = pk_bf(acc[mt][nt][2] + bv, acc[mt][nt][3] + bv);
          uint2 val; val.x = p0; val.y = p1;
          // vt4 index = tok*192 rearranged: (tok>>2)*768 + d*4 + (tok&3)
          *reinterpret_cast<uint2*>(vt_out + (size_t)row * 192 + d * 4) = val;
        } else {
          #pragma unroll
          for (int r = 0; r < 4; ++r) {
            int rr = row + r;
            float v = acc[mt][nt][r] + bv;
            if (MODE == 0) {
              if (ncol < 192) q_out[(size_t)rr * CPAD + ncol] = f2bf(v);
              else k_out[(size_t)rr * CPAD + (ncol - 192)] = f2bf(v);
            } else {
              if (ncol < CDIM) outf[(size_t)rr * CDIM + ncol] = v + resid[(size_t)rr * CDIM + ncol];
            }
          }
        }
      }
    }
  }
}

// ---------------- attention: per (window, head) — zero LDS/barriers ---------
// S^T = K·Q^T; C-layout of S^T == A-layout of PV MFMA under key permutation
// key(kt,m) = 8*(m>>2) + 4*kt + (m&3). V in group-of-4 layout vt4 (coalesced
// 8B loads); OOB -> bias group at tok NTOK; K OOB -> bias row NTOK.
// Fixed-max softmax (Q pre-scaled by scale*log2e); l via V ones-column (d30).
__global__ __launch_bounds__(256, 4) void attn_k(const ushort_t* __restrict__ q_tok,
    const ushort_t* __restrict__ k_tok, const ushort_t* __restrict__ vt4,
    ushort_t* __restrict__ ao)
{
  const int w = blockIdx.x, h = blockIdx.y;
  const int tid = threadIdx.x;
  const int lane = tid & 63, wave = tid >> 6;
  const int quad = lane >> 4, l16 = lane & 15;
  const int wy = w >> 4, wx = w & 15;
  const int tok0 = wy * 16 * 256 + wx * 16;
  const int hc = h * 32;
  const int ybase = wy * 16 - 4, xbase = wx * 16 - 4;

  // Q fragments (B-operand layout), 4 q-tiles of 16
  bf16x8 qf[4];
  #pragma unroll
  for (int qt = 0; qt < 4; ++qt) {
    int qi = wave * 64 + qt * 16 + l16;
    int token = tok0 + (qi >> 4) * 256 + (qi & 15);
    qf[qt] = *reinterpret_cast<const bf16x8*>(q_tok + (size_t)token * CPAD + hc + quad * 8);
  }

  // permuted key id for the K A-frag gather
  const int key0 = ((l16 >> 2) << 3) + (l16 & 3);

  // hoisted patch geometry: p = 96*c3 + (32*cm + lanepat), lanepat < 96
  int kpy[3][2], ktx[3][2]; bool kxin[3][2];
  int vpy[3][2], vtx[3][2]; bool vxin[3][2];
  #pragma unroll
  for (int cm = 0; cm < 3; ++cm) {
    #pragma unroll
    for (int j = 0; j < 2; ++j) {
      int pk = 32 * cm + key0 + 4 * j;
      int py = pk / 24, px = pk - py * 24;
      kpy[cm][j] = py; ktx[cm][j] = xbase + px;
      kxin[cm][j] = (unsigned)(xbase + px) < 256u;
      int pv = 32 * cm + quad * 8 + 4 * j;
      int pyv = pv / 24, pxv = pv - pyv * 24;
      vpy[cm][j] = pyv; vtx[cm][j] = xbase + pxv;
      vxin[cm][j] = (unsigned)(xbase + pxv) < 256u;
    }
  }
  const int dOff0 = (hc + l16) * 4, dOff1 = (hc + 16 + l16) * 4;

  f32x4 o[4][2] = {};
  f32x4 zero = {0.f, 0.f, 0.f, 0.f};

  #pragma unroll
  for (int c = 0; c < 18; ++c) {
    const int cm = c % 3, c3 = c / 3;
    const int yrow = ybase + 4 * c3;
    // ---- K A-frags: per-lane 16B gathers
    bf16x8 kf[2];
    #pragma unroll
    for (int kt = 0; kt < 2; ++kt) {
      int y = yrow + kpy[cm][kt];
      bool inb = kxin[cm][kt] && ((unsigned)y < 256u);
      int t = inb ? (y * 256 + ktx[cm][kt]) : NTOK;
      kf[kt] = *reinterpret_cast<const bf16x8*>(k_tok + (size_t)t * CPAD + hc + quad * 8);
    }
    // ---- V B-frags: coalesced 8B loads from vt4 (4-token groups)
    unsigned vv[2][4];
    #pragma unroll
    for (int h2 = 0; h2 < 2; ++h2) {
      int y = yrow + vpy[cm][h2];
      bool inb = vxin[cm][h2] && ((unsigned)y < 256u);
      int t = inb ? (y * 256 + vtx[cm][h2]) : NTOK;
      const ushort_t* gp = vt4 + (size_t)t * 192;
      uint2 v0 = *reinterpret_cast<const uint2*>(gp + dOff0);
      uint2 v1 = *reinterpret_cast<const uint2*>(gp + dOff1);
      vv[0][h2 * 2] = v0.x; vv[0][h2 * 2 + 1] = v0.y;
      vv[1][h2 * 2] = v1.x; vv[1][h2 * 2 + 1] = v1.y;
    }
    bf16x8 vf[2];
    #pragma unroll
    for (int dt = 0; dt < 2; ++dt) {
      union { unsigned u[4]; bf16x8 v; } a_;
      a_.u[0] = vv[dt][0]; a_.u[1] = vv[dt][1];
      a_.u[2] = vv[dt][2]; a_.u[3] = vv[dt][3];
      vf[dt] = a_.v;
    }
    // ---- S^T = K Q^T (pre-scaled), raw v_exp, pack P in A-layout
    #pragma unroll
    for (int qt = 0; qt < 4; ++qt) {
      f32x4 s0 = __builtin_amdgcn_mfma_f32_16x16x32_bf16(kf[0], qf[qt], zero, 0, 0, 0);
      f32x4 s1 = __builtin_amdgcn_mfma_f32_16x16x32_bf16(kf[1], qf[qt], zero, 0, 0, 0);
      union { unsigned u[4]; bf16x8 v; } pk;
      pk.u[0] = pk_bf(__builtin_amdgcn_exp2f(s0[0]), __builtin_amdgcn_exp2f(s0[1]));
      pk.u[1] = pk_bf(__builtin_amdgcn_exp2f(s0[2]), __builtin_amdgcn_exp2f(s0[3]));
      pk.u[2] = pk_bf(__builtin_amdgcn_exp2f(s1[0]), __builtin_amdgcn_exp2f(s1[1]));
      pk.u[3] = pk_bf(__builtin_amdgcn_exp2f(s1[2]), __builtin_amdgcn_exp2f(s1[3]));
      #pragma unroll
      for (int dt = 0; dt < 2; ++dt)
        o[qt][dt] = __builtin_amdgcn_mfma_f32_16x16x32_bf16(pk.v, vf[dt], o[qt][dt], 0, 0, 0);
    }
  }

  // ---- epilogue: l = O[:,30] (ones-column), O /= l, scatter
  #pragma unroll
  for (int qt = 0; qt < 4; ++qt) {
    #pragma unroll
    for (int r = 0; r < 4; ++r) {
      float l = __shfl(o[qt][1][r], (lane & 48) + 14, 64);
      float inv = 1.0f / l;
      int qi = wave * 64 + qt * 16 + quad * 4 + r;
      int token = tok0 + (qi >> 4) * 256 + (qi & 15);
      ao[(size_t)token * CPAD + hc + l16]      = f2bf(o[qt][0][r] * inv);
      ao[(size_t)token * CPAD + hc + 16 + l16] = f2bf(o[qt][1][r] * inv);
    }
  }
}

// ---------------- launch ----------------
extern "C" void kernel_launch(void* const* d_in, const int* in_sizes, int n_in,
                              void* d_out, int out_size, void* d_ws, size_t ws_size,
                              hipStream_t stream) {
  const float* x      = (const float*)d_in[0];
  const float* norm_w = (const float*)d_in[1];
  const float* norm_b = (const float*)d_in[2];
  const float* q_w    = (const float*)d_in[3];
  const float* q_b    = (const float*)d_in[4];
  const float* kv_w   = (const float*)d_in[5];
  const float* kv_b   = (const float*)d_in[6];
  const float* p_w    = (const float*)d_in[7];
  const float* p_b    = (const float*)d_in[8];

  char* base = (char*)d_ws;
  size_t off = 0;
  auto alloc = [&](size_t bytes) { char* p = base + off; off = (off + bytes + 255) & ~(size_t)255; return p; };
  ushort_t* xn_p  = (ushort_t*)alloc((size_t)NTOK * CPAD * 2);        // reused as ao
  ushort_t* q_tok = (ushort_t*)alloc((size_t)NTOK * CPAD * 2);
  ushort_t* k_tok = (ushort_t*)alloc((size_t)(NTOK + 1) * CPAD * 2);  // +1 bias row
  ushort_t* vt4   = (ushort_t*)alloc((size_t)(NTOK + 4) * 192 * 2);   // +1 bias group
  ushort_t* wqkvt = (ushort_t*)alloc(576 * 192 * 2);
  ushort_t* pwt   = (ushort_t*)alloc(192 * 192 * 2);
  float* qkvb = (float*)alloc(576 * 4);
  float* pbp  = (float*)alloc(192 * 4);
  ushort_t* ao = xn_p;  // alias: attention does not read xn_p

  prep_k<<<583, 256, 0, stream>>>(q_w, q_b, kv_w, kv_b, p_w, p_b,
                                  wqkvt, pwt, qkvb, pbp,
                                  k_tok + (size_t)NTOK * CPAD,
                                  vt4 + (size_t)NTOK * 192);
  ln_k<<<NTOK / 4, 256, 0, stream>>>(x, norm_w, norm_b, xn_p);
  gemm_k<0><<<NTOK / 128, 256, 0, stream>>>(xn_p, wqkvt, qkvb, q_tok, k_tok, vt4, nullptr, nullptr);
  attn_k<<<dim3(256, 6), 256, 0, stream>>>(q_tok, k_tok, vt4, ao);
  gemm_k<1><<<NTOK / 128, 256, 0, stream>>>(ao, pwt, pbp, nullptr, nullptr, nullptr, (float*)d_out, x);
}